// Round 3
// baseline (153.205 us; speedup 1.0000x reference)
//
#include <hip/hip_runtime.h>

#define B_ROWS 8192
#define DIM    128
#define TILE   256
#define LDK    136          // padded LDS row stride (bf16): 272 B -> rows 4 banks apart, b128 phases tile all 32 banks
#define GRID_T (B_ROWS / TILE)
#define NBLOCKS_TOTAL (GRID_T * GRID_T * 2)

typedef __attribute__((ext_vector_type(8)))  __bf16 bf16x8;
typedef __attribute__((ext_vector_type(2)))  __bf16 bf16x2;
typedef __attribute__((ext_vector_type(16))) float  f32x16;

// sqrt(log2(e)/0.07): fold temperature+log2e symmetrically into both row scales.
#define RBSCALE 4.5398172f

// One wave per row: fp32 -> bf16 convert + scaled reciprocal norm. Also zeroes acc/counter.
__global__ __launch_bounds__(256)
void prep_kernel(const float* __restrict__ e1, const float* __restrict__ e2,
                 __bf16* __restrict__ b1, __bf16* __restrict__ b2,
                 float* __restrict__ rb1, float* __restrict__ rb2,
                 float* __restrict__ acc) {
    if (blockIdx.x == 0 && threadIdx.x < 4) acc[threadIdx.x] = 0.f;  // acc[0],acc[1],counter,pad
    int gw   = (blockIdx.x * 256 + threadIdx.x) >> 6;
    int lane = threadIdx.x & 63;
    const float* src; __bf16* dst; float* rb; int row;
    if (gw < B_ROWS) { src = e1; dst = b1; rb = rb1; row = gw; }
    else             { src = e2; dst = b2; rb = rb2; row = gw - B_ROWS; }
    float2 v = ((const float2*)(src + (size_t)row * DIM))[lane];
    float ss = v.x * v.x + v.y * v.y;
    bf16x2 p = { (__bf16)v.x, (__bf16)v.y };
    *(bf16x2*)(dst + (size_t)row * DIM + 2 * lane) = p;
#pragma unroll
    for (int o = 32; o > 0; o >>= 1) ss += __shfl_down(ss, o);
    if (lane == 0) rb[row] = RBSCALE / sqrtf(ss);
}

template <bool MASKED>
__device__ __forceinline__ float epilogue_sum(const f32x16 acc[2][4],
                                              const float* sR, const float* sC,
                                              int i0, int c0, int wr, int wc, int l, int h) {
    float nc[4];
#pragma unroll
    for (int t = 0; t < 4; ++t) nc[t] = sC[wc * 128 + t * 32 + l];
    float s = 0.f;
#pragma unroll
    for (int g = 0; g < 2; ++g) {
#pragma unroll
        for (int q = 0; q < 4; ++q) {
            float4 rn4 = *(const float4*)&sR[wr * 64 + g * 32 + 8 * q + 4 * h];
            float rn[4] = { rn4.x, rn4.y, rn4.z, rn4.w };
#pragma unroll
            for (int t = 0; t < 4; ++t) {
#pragma unroll
                for (int rr = 0; rr < 4; ++rr) {
                    float arg = acc[g][t][q * 4 + rr] * rn[rr] * nc[t];
                    float ev  = exp2f(arg);
                    if (MASKED) {
                        int i = i0 + wr * 64 + g * 32 + 8 * q + 4 * h + rr;
                        int c = c0 + wc * 128 + t * 32 + l;
                        int d = c - i; d += (d >> 31) & B_ROWS;   // (c-i) mod B
                        s += (d > i) ? ev : 0.f;
                    } else {
                        s += ev;
                    }
                }
            }
        }
    }
    return s;
}

// One 256x256 tile of sim11 (z=0, masked) or sim12 (z=1) per block. 512 threads, 8 waves,
// each wave computes a 64x128 patch as 2x4 blocking of 32x32x16 MFMA.
__global__ __launch_bounds__(512, 2)
void pair_kernel(const __bf16* __restrict__ E1, const __bf16* __restrict__ E2,
                 const float* __restrict__ RB1, const float* __restrict__ RB2,
                 float* __restrict__ accg, float* __restrict__ out) {
    const int z  = blockIdx.z;
    const int i0 = blockIdx.y * TILE, c0 = blockIdx.x * TILE;

    bool skip = false, masked = false;
    if (z == 0) {
        int D = c0 - i0;
        int e = (D > 0) ? D : D + B_ROWS;      // D==0 -> B (diagonal tiles always included+masked)
        skip   = (e + (TILE - 1) <= i0);       // fully excluded tile
        masked = (D == 0) || (e < i0 + 2 * TILE - 1);
    }

    if (!skip) {
        const __bf16* Bsrc = (z == 0) ? E1 : E2;
        const float*  RC   = (z == 0) ? RB1 : RB2;

        __shared__ __align__(16) __bf16 As[TILE * LDK];
        __shared__ __align__(16) __bf16 Bs[TILE * LDK];
        __shared__ __align__(16) float sR[TILE];
        __shared__ __align__(16) float sC[TILE];
        __shared__ float red[8];

        const int tid = threadIdx.x;
#pragma unroll
        for (int it = 0; it < 8; ++it) {
            int idx = tid + it * 512;
            int r = idx >> 4, ch = idx & 15;
            *(uint4*)(&As[r * LDK + ch * 8]) = *(const uint4*)(E1   + (size_t)(i0 + r) * DIM + ch * 8);
            *(uint4*)(&Bs[r * LDK + ch * 8]) = *(const uint4*)(Bsrc + (size_t)(c0 + r) * DIM + ch * 8);
        }
        if (tid < TILE) sR[tid] = RB1[i0 + tid];
        else if (tid < 2 * TILE) sC[tid - TILE] = RC[c0 + tid - TILE];
        __syncthreads();

        const int wave = tid >> 6, lane = tid & 63;
        const int wr = wave >> 1, wc = wave & 1;     // 4 row-groups x 2 col-groups
        const int l  = lane & 31, h = lane >> 5;

        f32x16 acc[2][4];
#pragma unroll
        for (int g = 0; g < 2; ++g)
#pragma unroll
            for (int t = 0; t < 4; ++t)
#pragma unroll
                for (int q = 0; q < 16; ++q) acc[g][t][q] = 0.f;

        const __bf16* Ap = &As[(wr * 64  + l) * LDK + h * 8];
        const __bf16* Bp = &Bs[(wc * 128 + l) * LDK + h * 8];
#pragma unroll
        for (int s = 0; s < 8; ++s) {
            bf16x8 a0 = *(const bf16x8*)(Ap + s * 16);
            bf16x8 a1 = *(const bf16x8*)(Ap + 32 * LDK + s * 16);
            bf16x8 b0 = *(const bf16x8*)(Bp + s * 16);
            bf16x8 b1 = *(const bf16x8*)(Bp + 32 * LDK + s * 16);
            bf16x8 b2 = *(const bf16x8*)(Bp + 64 * LDK + s * 16);
            bf16x8 b3 = *(const bf16x8*)(Bp + 96 * LDK + s * 16);
            acc[0][0] = __builtin_amdgcn_mfma_f32_32x32x16_bf16(a0, b0, acc[0][0], 0, 0, 0);
            acc[0][1] = __builtin_amdgcn_mfma_f32_32x32x16_bf16(a0, b1, acc[0][1], 0, 0, 0);
            acc[0][2] = __builtin_amdgcn_mfma_f32_32x32x16_bf16(a0, b2, acc[0][2], 0, 0, 0);
            acc[0][3] = __builtin_amdgcn_mfma_f32_32x32x16_bf16(a0, b3, acc[0][3], 0, 0, 0);
            acc[1][0] = __builtin_amdgcn_mfma_f32_32x32x16_bf16(a1, b0, acc[1][0], 0, 0, 0);
            acc[1][1] = __builtin_amdgcn_mfma_f32_32x32x16_bf16(a1, b1, acc[1][1], 0, 0, 0);
            acc[1][2] = __builtin_amdgcn_mfma_f32_32x32x16_bf16(a1, b2, acc[1][2], 0, 0, 0);
            acc[1][3] = __builtin_amdgcn_mfma_f32_32x32x16_bf16(a1, b3, acc[1][3], 0, 0, 0);
        }

        // C/D layout (m74/m101): col = lane&31, row = (reg&3) + 8*(reg>>2) + 4*(lane>>5).
        float s_local = masked
            ? epilogue_sum<true >(acc, sR, sC, i0, c0, wr, wc, l, h)
            : epilogue_sum<false>(acc, sR, sC, i0, c0, wr, wc, l, h);

#pragma unroll
        for (int o = 32; o > 0; o >>= 1) s_local += __shfl_down(s_local, o);
        if (lane == 0) red[wave] = s_local;
        __syncthreads();
        if (tid == 0) {
            float tot = red[0] + red[1] + red[2] + red[3] + red[4] + red[5] + red[6] + red[7];
            atomicAdd(&accg[z], tot);
        }
    }

    // Completion counter: last block (of all 2048, incl. skipped) computes the final output.
    if (threadIdx.x == 0) {
        __threadfence();
        unsigned prev = atomicAdd((unsigned*)&accg[2], 1u);
        if (prev == NBLOCKS_TOTAL - 1) {
            float l1 = atomicAdd(&accg[0], 0.f);   // atomic read-back: device-coherent
            float l2 = atomicAdd(&accg[1], 0.f);
            out[0] = -logf(l1 / l2);
        }
    }
}

extern "C" void kernel_launch(void* const* d_in, const int* in_sizes, int n_in,
                              void* d_out, int out_size, void* d_ws, size_t ws_size,
                              hipStream_t stream) {
    (void)in_sizes; (void)n_in; (void)out_size; (void)ws_size;
    const float* e1 = (const float*)d_in[0];
    const float* e2 = (const float*)d_in[1];
    float* out = (float*)d_out;
    char*  ws  = (char*)d_ws;

    float*  acc = (float*)ws;                               // 16 B: l1, l2, done-counter, pad
    float*  rb1 = (float*)(ws + 4096);                      // 32 KB
    float*  rb2 = (float*)(ws + 4096 + 32768);              // 32 KB
    __bf16* b1  = (__bf16*)(ws + 69632);                    // 2 MB
    __bf16* b2  = (__bf16*)(ws + 69632 + 2097152);          // 2 MB

    prep_kernel<<<dim3(4096), dim3(256), 0, stream>>>(e1, e2, b1, b2, rb1, rb2, acc);
    pair_kernel<<<dim3(GRID_T, GRID_T, 2), dim3(512), 0, stream>>>(b1, b2, rb1, rb2, acc, out);
}

// Round 4
// 112.422 us; speedup vs baseline: 1.3628x; 1.3628x over previous
//
#include <hip/hip_runtime.h>

#define B_ROWS   8192
#define BMASK    8191
#define DIM      128
#define CTILE    64          // columns per tile
#define CHUNK    16          // col-tiles per block
#define BLK64    16384       // bytes per packed 64-row block (64*128*2)

typedef __attribute__((ext_vector_type(8)))  __bf16 bf16x8;
typedef __attribute__((ext_vector_type(2)))  __bf16 bf16x2;
typedef __attribute__((ext_vector_type(16))) float  f32x16;

// sqrt(log2(e)/0.07) folded symmetrically into both row normalizations.
#define RBSCALE 4.5398159f

__device__ __forceinline__ float fast_exp2(float x) {
#if __has_builtin(__builtin_amdgcn_exp2f)
    return __builtin_amdgcn_exp2f(x);
#else
    return exp2f(x);
#endif
}

// One wave per row: norm -> scale -> bf16 -> k-major packed layout
// packed[row>>6][granule=k/8][row&63][8 bf16]. Block 0 zeroes accumulators.
__global__ __launch_bounds__(256)
void prep_kernel(const float* __restrict__ e1, const float* __restrict__ e2,
                 char* __restrict__ p1, char* __restrict__ p2,
                 float* __restrict__ acc) {
    if (blockIdx.x == 0 && threadIdx.x < 4) acc[threadIdx.x] = 0.f;
    int gw   = (blockIdx.x * 256 + threadIdx.x) >> 6;   // 0..16383
    int lane = threadIdx.x & 63;
    const float* src; char* dst; int row;
    if (gw < B_ROWS) { src = e1; dst = p1; row = gw; }
    else             { src = e2; dst = p2; row = gw - B_ROWS; }
    float2 v = ((const float2*)(src + (size_t)row * DIM))[lane];
    float ss = v.x * v.x + v.y * v.y;
#pragma unroll
    for (int o = 32; o > 0; o >>= 1) ss += __shfl_xor(ss, o);   // butterfly: all lanes get total
    float rb = RBSCALE / sqrtf(ss);
    bf16x2 pk = { (__bf16)(v.x * rb), (__bf16)(v.y * rb) };
    size_t off = (size_t)(row >> 6) * BLK64 + (size_t)(lane >> 2) * 1024
               + (size_t)(row & 63) * 16 + (size_t)(lane & 3) * 4;
    *(bf16x2*)(dst + off) = pk;
}

template <bool MASKED>
__device__ __forceinline__ float tile_sum(const f32x16& a0, const f32x16& a1,
                                          int i00, int c) {
    float s = 0.f;
#pragma unroll
    for (int g = 0; g < 2; ++g) {
        const f32x16& a = g ? a1 : a0;
        int ib = i00 + g * 32;
#pragma unroll
        for (int r = 0; r < 16; ++r) {
            float ev = fast_exp2(a[r]);
            if (MASKED) {
                int i = ib + (r & 3) + 8 * (r >> 2);   // m74/m101 C/D row map
                int d = (c - i) & BMASK;               // (c-i) mod B
                s += (d > i) ? ev : 0.f;
            } else {
                s += ev;
            }
        }
    }
    return s;
}

// Persistent-panel blocks: 128-row A panel in registers, loop over 64-col B tiles
// double-buffered via async global_load_lds. 256 threads = 4 waves:
// w>>1 = row half (64 rows), w&1 = col half (32 cols).
__global__ __launch_bounds__(256, 3)
void pair_kernel(const char* __restrict__ P1, const char* __restrict__ P2,
                 float* __restrict__ accg, float* __restrict__ out,
                 int nz0, int nblocks) {
    __shared__ __align__(16) __bf16 Bbuf[2][8192];   // 2 x 16 KB
    __shared__ float red[4];

    const int tid  = threadIdx.x;
    const int b    = blockIdx.x;

    // ---- block -> (z, panel p, tile chunk [k0,k1)) ----
    int z, p, k0, k1;
    if (b < nz0) {
        z = 0;
        int accb = 0; p = 0;
        for (;; ++p) {
            int i0t = 128 * p;
            int e1t = (i0t > 128) ? i0t : 128;
            int cnt = 2 + (B_ROWS - e1t) / 64;
            int nb  = (cnt + CHUNK - 1) >> 4;
            if (b < accb + nb) {
                int s = b - accb;
                k0 = s * CHUNK;
                k1 = (k0 + CHUNK < cnt) ? (k0 + CHUNK) : cnt;
                break;
            }
            accb += nb;
        }
    } else {
        z = 1;
        int j = b - nz0;
        p = j >> 3;
        k0 = (j & 7) * CHUNK;
        k1 = k0 + CHUNK;
    }
    const int i0 = 128 * p;
    const int e1 = (i0 > 128) ? i0 : 128;

    const char* Bpack = (z == 0) ? P1 : P2;

    // tile index k -> column origin c0; masked flag (z=0 only)
    auto tile_c0 = [&](int k) -> int {
        if (z) return k * CTILE;
        int e = (k == 0) ? 64 : e1 + (k - 1) * 64;
        return (i0 + e) & BMASK;
    };
    auto tile_masked = [&](int k) -> bool {
        if (z) return false;
        int e = (k == 0) ? 64 : e1 + (k - 1) * 64;
        return (e < i0 + 256) || (e > 8128);
    };

    const int w  = tid >> 6, lane = tid & 63;
    const int w2 = w >> 1, wc = w & 1;
    const int l  = lane & 31, h = lane >> 5;

    // ---- A panel -> registers: rows i0 + w2*64 + [0,64), k-major packed ----
    bf16x8 af[2][8];
    {
        const char* ap = P1 + (size_t)(p * 2 + w2) * BLK64;
#pragma unroll
        for (int g = 0; g < 2; ++g)
#pragma unroll
            for (int s = 0; s < 8; ++s)
                af[g][s] = *(const bf16x8*)(ap + (size_t)(s * 2 + h) * 1024
                                               + (size_t)(g * 32 + l) * 16);
    }

    // ---- async stage: 16 KB tile, lane-linear (256 thr x 16 B x 4 rounds) ----
    auto stage = [&](int bufi, int k) {
        const char* gp = Bpack + (size_t)(tile_c0(k) >> 6) * BLK64 + (size_t)tid * 16;
        char*       lp = (char*)&Bbuf[bufi][0] + (size_t)tid * 16;
#pragma unroll
        for (int r = 0; r < 4; ++r)
            __builtin_amdgcn_global_load_lds(
                (const __attribute__((address_space(1))) unsigned int*)(gp + r * 4096),
                (__attribute__((address_space(3))) unsigned int*)(lp + r * 4096),
                16, 0, 0);
    };

    const int i00 = i0 + w2 * 64 + 4 * h;   // epilogue row base for this lane
    const int cb  = wc * 32 + l;            // col offset within tile

    float sacc = 0.f;
    stage(0, k0);
    int cur = 0;
    for (int k = k0; k < k1; ++k) {
        __syncthreads();                     // buf[cur] staged; prev compute done
        if (k + 1 < k1) stage(cur ^ 1, k + 1);

        f32x16 a0, a1;
#pragma unroll
        for (int r = 0; r < 16; ++r) { a0[r] = 0.f; a1[r] = 0.f; }

        const char* bb = (const char*)&Bbuf[cur][0] + (size_t)cb * 16 + (size_t)h * 1024;
#pragma unroll
        for (int s = 0; s < 8; ++s) {
            bf16x8 bf = *(const bf16x8*)(bb + (size_t)s * 2048);
            a0 = __builtin_amdgcn_mfma_f32_32x32x16_bf16(af[0][s], bf, a0, 0, 0, 0);
            a1 = __builtin_amdgcn_mfma_f32_32x32x16_bf16(af[1][s], bf, a1, 0, 0, 0);
        }

        int c = tile_c0(k) + cb;
        sacc += tile_masked(k) ? tile_sum<true >(a0, a1, i00, c)
                               : tile_sum<false>(a0, a1, i00, c);
        cur ^= 1;
    }

#pragma unroll
    for (int o = 32; o > 0; o >>= 1) sacc += __shfl_down(sacc, o);
    if (lane == 0) red[w] = sacc;
    __syncthreads();
    if (tid == 0) {
        atomicAdd(&accg[z], red[0] + red[1] + red[2] + red[3]);
        __threadfence();
        unsigned prev = atomicAdd((unsigned*)&accg[2], 1u);
        if (prev == (unsigned)(nblocks - 1)) {
            float l1 = atomicAdd(&accg[0], 0.f);
            float l2 = atomicAdd(&accg[1], 0.f);
            out[0] = -logf(l1 / l2);
        }
    }
}

extern "C" void kernel_launch(void* const* d_in, const int* in_sizes, int n_in,
                              void* d_out, int out_size, void* d_ws, size_t ws_size,
                              hipStream_t stream) {
    (void)in_sizes; (void)n_in; (void)out_size; (void)ws_size;
    const float* e1 = (const float*)d_in[0];
    const float* e2 = (const float*)d_in[1];
    float* out = (float*)d_out;
    char*  ws  = (char*)d_ws;

    float* acc = (float*)ws;                       // 16 B: l1, l2, counter, pad
    char*  p1  = ws + 4096;                        // 2 MB packed E1
    char*  p2  = ws + 4096 + 2097152;              // 2 MB packed E2

    // z0 block count (must match device-side mapping)
    int nz0 = 0;
    for (int p = 0; p < 64; ++p) {
        int i0 = 128 * p;
        int e1t = (i0 > 128) ? i0 : 128;
        int cnt = 2 + (B_ROWS - e1t) / 64;
        nz0 += (cnt + CHUNK - 1) / CHUNK;
    }
    int nblocks = nz0 + 512;

    prep_kernel<<<dim3(4096), dim3(256), 0, stream>>>(e1, e2, p1, p2, acc);
    pair_kernel<<<dim3(nblocks), dim3(256), 0, stream>>>(p1, p2, acc, out, nz0, nblocks);
}